// Round 15
// baseline (873.747 us; speedup 1.0000x reference)
//
#include <hip/hip_runtime.h>
#include <hip/hip_bf16.h>
#include <hip/hip_fp16.h>

#define NN 50000
#define EE 500000
#define EP 550000
#define GG 64

typedef const __hip_bfloat16* bfp;

__device__ __forceinline__ int clampN(int v) { return (int)(((unsigned)v) % (unsigned)NN); }

// DPP helpers (VALU pipe only, no DS)
#define DPP_ADD(x, ctrl) \
  ((x) + __int_as_float(__builtin_amdgcn_update_dpp(0, __float_as_int(x), ctrl, 0xF, 0xF, true)))

__device__ __forceinline__ float red8(float v) {   // sum over 8-lane slot
  v = DPP_ADD(v, 0xB1);    // xor1
  v = DPP_ADD(v, 0x4E);    // xor2
  v = DPP_ADD(v, 0x141);   // row_half_mirror == xor4 once quad-uniform
  return v;
}

__device__ __forceinline__ float row_red16(float v) {
  v = DPP_ADD(v, 0xB1);
  v = DPP_ADD(v, 0x4E);
  v = DPP_ADD(v, 0x141);
  v = DPP_ADD(v, 0x140);   // row_mirror == xor8 once 8-uniform
  return v;
}

// TRUE xor butterfly across slots (valid for arbitrary per-lane values).
// r12/r13 BUG: DPP row_mirror is xor8 only for 8-uniform values — acc[] is
// per-lane-distinct, so channels got cross-mixed (~2% err). r14 fix attempt
// used ds_swizzle with a runtime pattern (must be a literal constant) -> CE.
// v15: __shfl_xor lowers to ds_bpermute, correct for any per-lane values.
__device__ __forceinline__ float cross8x(float v) {
  v += __shfl_xor(v, 8, 64);
  v += __shfl_xor(v, 16, 64);
  v += __shfl_xor(v, 32, 64);
  return v;
}

__device__ __forceinline__ float rlane(float v, int l) {
  return __int_as_float(__builtin_amdgcn_readlane(__float_as_int(v), l));
}

__global__ void k_probe_v7(const unsigned short* xraw, int* flag) {
  if (threadIdx.x != 0 || blockIdx.x != 0) return;
  int cnt = 0;
  for (int i = 0; i < 64; i++) {
    unsigned u = ((unsigned)xraw[i]) << 16;
    float v = __uint_as_float(u);
    float a = fabsf(v);
    if (a >= 1e-5f && a <= 100.f) cnt++;
  }
  flag[0] = (cnt >= 56) ? 1 : 0;
}

struct Cvt24 {
  const void* src[24];
  float* dst[24];
  int start[25];
};

__global__ void k_cvtall_v8(Cvt24 d, const int* flag, int total) {
  int idx = blockIdx.x * 256 + threadIdx.x;
  if (idx >= total) return;
  int lo = 0, hi = 24;
  while (hi - lo > 1) {
    int mid = (lo + hi) >> 1;
    if (idx >= d.start[mid]) lo = mid; else hi = mid;
  }
  int i = idx - d.start[lo];
  if (flag[0]) d.dst[lo][i] = __bfloat162float(((bfp)d.src[lo])[i]);
  else         d.dst[lo][i] = ((const float*)d.src[lo])[i];
}

__global__ void k_zero_v7(int* p, int n) {
  int i = blockIdx.x * 256 + threadIdx.x;
  if (i < n) p[i] = 0;
}

__global__ void k_count_v7(const int* ei, const float* ea, int* deg, float* asum) {
  int e = blockIdx.x * 256 + threadIdx.x;
  if (e >= EE) return;
  int dst = clampN(ei[EE + e]);
  atomicAdd(&deg[dst], 1);
  atomicAdd(&asum[2 * dst],     ea[2 * e]);
  atomicAdd(&asum[2 * dst + 1], ea[2 * e + 1]);
}

__global__ void k_scan_v7(const int* deg, int* offs) {
  __shared__ int part[256];
  int t = threadIdx.x;
  int npt = (NN + 255) / 256;
  int lo = t * npt;
  int hi = lo + npt;
  if (hi > NN) hi = NN;
  int sum = 0;
  for (int i = lo; i < hi; i++) sum += deg[i] + 1;
  part[t] = sum;
  __syncthreads();
  for (int o = 1; o < 256; o <<= 1) {
    int add = (t >= o) ? part[t - o] : 0;
    __syncthreads();
    part[t] += add;
    __syncthreads();
  }
  int base = part[t] - sum;
  for (int i = lo; i < hi; i++) {
    offs[i] = base;
    base += deg[i] + 1;
  }
  if (t == 255) offs[NN] = part[255];
}

// self-loop mean folded in
__global__ void k_scatter_v12(const int* ei, const float* ea,
                              const int* deg, const float* asum,
                              const int* offs, int* cursor, float4* recs) {
  int e = blockIdx.x * 256 + threadIdx.x;
  if (e >= EP) return;
  int dst, src;
  float a0, a1;
  if (e < EE) {
    dst = clampN(ei[EE + e]);
    src = clampN(ei[e]);
    a0 = ea[2 * e];
    a1 = ea[2 * e + 1];
  } else {
    dst = e - EE;
    src = dst;
    float d = (float)deg[dst];
    if (d < 1.f) d = 1.f;
    a0 = asum[2 * dst] / d;
    a1 = asum[2 * dst + 1] / d;
  }
  int pos = offs[dst] + atomicAdd(&cursor[dst], 1);
  if (pos >= 0 && pos < EP)
    recs[pos] = make_float4(__int_as_float(src), a0, a1, 0.f);
}

// GAT1: 4 waves x 4 nodes, DPP row-reduce, block-wide lin2 GEMM epilogue;
// xl2 stored FP16-packed (rel err 2^-12, negligible downstream).
__global__ void k_gat1_v13(const float* x,
                           const float* Wl, const float* bl,
                           const float* Wr, const float* br,
                           const float* We, const float* att, const float* bias,
                           const float* Wl2, const float* bl2,
                           const float* Wr2, const float* br2,
                           const int* offs, const float4* recs,
                           unsigned* xl2p, float* xr2) {
  __shared__ float hS[16 * 256];
  int t = threadIdx.x;
  int w = t >> 6;
  int l = t & 63;
  int g = l >> 4;
  int m = l & 15;
  int ibase = blockIdx.x * 16;
  float wl[4][5], wr[4][5], we0v[4], we1v[4], attv[4], blv[4], brv[4], biasv[4];
#pragma unroll
  for (int q = 0; q < 4; q++) {
    int j = g * 64 + m + 16 * q;
#pragma unroll
    for (int k = 0; k < 5; k++) {
      wl[q][k] = Wl[k * 256 + j];
      wr[q][k] = Wr[k * 256 + j];
    }
    we0v[q] = We[j];
    we1v[q] = We[256 + j];
    attv[q] = att[j];
    blv[q] = bl[j];
    brv[q] = br[j];
    biasv[q] = bias[j];
  }
  for (int nn = 0; nn < 4; nn++) {
    int i = ibase + w * 4 + nn;
    if (i >= NN) break;
    float xi[5];
#pragma unroll
    for (int k = 0; k < 5; k++) xi[k] = x[i * 5 + k];
    float xrv[4];
#pragma unroll
    for (int q = 0; q < 4; q++) {
      float a = brv[q];
#pragma unroll
      for (int k = 0; k < 5; k++) a += xi[k] * wr[q][k];
      xrv[q] = a;
    }
    int p0 = offs[i], p1 = offs[i + 1];
    float s = 0.f;
    float acc[4] = {0.f, 0.f, 0.f, 0.f};
    for (int base = p0; base < p1; base += 8) {
      int rem = p1 - base;
      int idx = base + (l & 7);
      if (idx >= p1) idx = p1 - 1;
      float4 rec = recs[idx];
      float xa0 = 0.f, xa1 = 0.f, xa2 = 0.f, xa3 = 0.f, xa4 = 0.f;
      if (l < 8) {
        const float* xp = x + (size_t)__float_as_int(rec.x) * 5;
        xa0 = xp[0]; xa1 = xp[1]; xa2 = xp[2]; xa3 = xp[3]; xa4 = xp[4];
      }
#pragma unroll
      for (int j = 0; j < 8; j++) {
        if (j >= rem) break;
        float xs0 = rlane(xa0, j), xs1 = rlane(xa1, j), xs2 = rlane(xa2, j),
              xs3 = rlane(xa3, j), xs4 = rlane(xa4, j);
        float ea0 = rlane(rec.y, j), ea1 = rlane(rec.z, j);
        float xlv[4];
        float v = 0.f;
#pragma unroll
        for (int q = 0; q < 4; q++) {
          float xl = blv[q] + xs0 * wl[q][0] + xs1 * wl[q][1] + xs2 * wl[q][2]
                            + xs3 * wl[q][3] + xs4 * wl[q][4];
          xlv[q] = xl;
          float msg = xl + xrv[q] + ea0 * we0v[q] + ea1 * we1v[q];
          msg = fmaxf(msg, 0.2f * msg);
          v += msg * attv[q];
        }
        v = row_red16(v);
        float wgt = __expf(v);
        s += wgt;
#pragma unroll
        for (int q = 0; q < 4; q++) acc[q] += wgt * xlv[q];
      }
    }
#pragma unroll
    for (int q = 0; q < 4; q++) {
      float o = acc[q] / s + biasv[q];
      o = (o > 0.f) ? o : (__expf(o) - 1.0f);
      hS[(w * 4 + nn) * 256 + g * 64 + m + 16 * q] = o;
    }
  }
  __syncthreads();
  int c = t & 63;
  int q4 = t >> 6;
  float accl[4] = {0.f, 0.f, 0.f, 0.f};
  float accr[4] = {0.f, 0.f, 0.f, 0.f};
  for (int k = 0; k < 256; k++) {
    float wlv = Wl2[k * 64 + c];
    float wrv = Wr2[k * 64 + c];
#pragma unroll
    for (int n = 0; n < 4; n++) {
      float hv = hS[(q4 * 4 + n) * 256 + k];
      accl[n] += hv * wlv;
      accr[n] += hv * wrv;
    }
  }
  float blc = bl2[c];
  float brc = br2[c];
#pragma unroll
  for (int n = 0; n < 4; n++) {
    int i = ibase + q4 * 4 + n;
    if (i < NN) {
      float vl = accl[n] + blc;
      xr2[(size_t)i * 64 + c] = accr[n] + brc;
      float vo = __int_as_float(__shfl_xor(__float_as_int(vl), 1, 64));
      if ((c & 1) == 0) {                    // even lane packs (self, odd-neighbor)
        __half2 h2 = __floats2half2_rn(vl, vo);
        xl2p[(size_t)i * 32 + (c >> 1)] = *reinterpret_cast<unsigned*>(&h2);
      }
    }
  }
}

// GAT2: wave per node; lane = (slot r=l>>3, 8 channels j*8..). 8 edges in
// flight; fp16-packed xl2 gather; cross-slot reduce via TRUE xor butterfly.
__global__ void k_gat2_v15(const float* We, const float* att, const float* bias,
                           const int* offs, const float4* recs,
                           const uint4* xl2p, const float* xr2, const int* batch,
                           float* pooled_r, int* gcnt_r) {
  int i = blockIdx.x * 4 + (threadIdx.x >> 6);
  if (i >= NN) return;
  int l = threadIdx.x & 63;
  int r = l >> 3;
  int j = l & 7;
  int ch0 = j * 8;
  float we0v[8], we1v[8], attv[8], xrcv[8];
#pragma unroll
  for (int cc = 0; cc < 8; cc++) {
    we0v[cc] = We[ch0 + cc];
    we1v[cc] = We[64 + ch0 + cc];
    attv[cc] = att[ch0 + cc];
    xrcv[cc] = xr2[(size_t)i * 64 + ch0 + cc];
  }
  int p0 = offs[i], p1 = offs[i + 1];
  float s = 0.f;
  float acc[8] = {0.f, 0.f, 0.f, 0.f, 0.f, 0.f, 0.f, 0.f};
  for (int base = p0; base < p1; base += 8) {
    int eidx = base + r;
    bool valid = eidx < p1;
    float4 rec = recs[valid ? eidx : (p1 - 1)];
    uint4 pk = xl2p[(size_t)__float_as_int(rec.x) * 8 + j];
    float xl[8];
    {
      __half2 h0 = *reinterpret_cast<__half2*>(&pk.x);
      __half2 h1 = *reinterpret_cast<__half2*>(&pk.y);
      __half2 h2 = *reinterpret_cast<__half2*>(&pk.z);
      __half2 h3 = *reinterpret_cast<__half2*>(&pk.w);
      xl[0] = __low2float(h0);  xl[1] = __high2float(h0);
      xl[2] = __low2float(h1);  xl[3] = __high2float(h1);
      xl[4] = __low2float(h2);  xl[5] = __high2float(h2);
      xl[6] = __low2float(h3);  xl[7] = __high2float(h3);
    }
    float v = 0.f;
#pragma unroll
    for (int cc = 0; cc < 8; cc++) {
      float msg = xl[cc] + xrcv[cc] + rec.y * we0v[cc] + rec.z * we1v[cc];
      msg = fmaxf(msg, 0.2f * msg);
      v += msg * attv[cc];
    }
    v = red8(v);                        // this edge's logit (slot-uniform)
    float w = valid ? __expf(v) : 0.f;
    s += w;
#pragma unroll
    for (int cc = 0; cc < 8; cc++) acc[cc] += w * xl[cc];
  }
  s = cross8x(s);                       // TRUE xor8/16/32 butterfly
#pragma unroll
  for (int cc = 0; cc < 8; cc++) acc[cc] = cross8x(acc[cc]);
  if (r == 0) {
    int gsl = (int)(((unsigned)batch[i]) % (unsigned)GG);
    int rep = i & 15;
#pragma unroll
    for (int cc = 0; cc < 8; cc++) {
      float o = acc[cc] / s + bias[ch0 + cc];
      o = (o > 0.f) ? o : (__expf(o) - 1.0f);
      atomicAdd(&pooled_r[rep * (GG * 64) + gsl * 64 + ch0 + cc], o);
    }
    if (j == 0) atomicAdd(&gcnt_r[rep * GG + gsl], 1);
  }
}

__global__ void k_poolsum_v9(const float* pooled_r, const int* gcnt_r,
                             float* pooled, int* gcnt) {
  int i = blockIdx.x * 256 + threadIdx.x;
  if (i < GG * 64) {
    float a = 0.f;
    for (int r = 0; r < 16; r++) a += pooled_r[r * (GG * 64) + i];
    pooled[i] = a;
  }
  if (i < GG) {
    int a = 0;
    for (int r = 0; r < 16; r++) a += gcnt_r[r * GG + i];
    gcnt[i] = a;
  }
}

__global__ void k_gin_v7(const float* pooled, const int* gcnt,
                         const float* Wi, const float* bi, float* GI) {
  int idx = blockIdx.x * 256 + threadIdx.x;
  if (idx >= GG * 192) return;
  int ts = idx / 192;
  int j = idx % 192;
  float a = 0.f;
  for (int k = 0; k < 64; k++) a += pooled[ts * 64 + k] * Wi[k * 192 + j];
  float cnt = (float)gcnt[ts];
  if (cnt < 1.f) cnt = 1.f;
  GI[idx] = a / cnt + bi[j];
}

// GRU + classifier; f32 output.
__global__ void k_gru_v12(const float* GI, const float* Wh, const float* bh,
                          const float* Wc1, const float* bc1,
                          const float* Wc2, const float* bc2, float* out) {
  __shared__ float WhS[64 * 192];
  __shared__ float hS[64];
  __shared__ float ghS[192];
  __shared__ float zc[32];
  int t = threadIdx.x;
  for (int idx = t; idx < 64 * 192; idx += 256) WhS[idx] = Wh[idx];
  if (t < 64) hS[t] = 0.f;
  __syncthreads();
  for (int ts = 0; ts < GG; ++ts) {
    if (t < 192) {
      float a = bh[t];
#pragma unroll 8
      for (int k = 0; k < 64; k++) a += hS[k] * WhS[k * 192 + t];
      ghS[t] = a;
    }
    __syncthreads();
    if (t < 64) {
      float r = 1.f / (1.f + expf(-(GI[ts * 192 + t] + ghS[t])));
      float z = 1.f / (1.f + expf(-(GI[ts * 192 + 64 + t] + ghS[64 + t])));
      float n = tanhf(GI[ts * 192 + 128 + t] + r * ghS[128 + t]);
      hS[t] = (1.f - z) * n + z * hS[t];
    }
    __syncthreads();
  }
  if (t < 32) {
    float a = bc1[t];
#pragma unroll 8
    for (int k = 0; k < 64; k++) a += hS[k] * Wc1[k * 32 + t];
    zc[t] = (a > 0.f) ? a : 0.f;
  }
  __syncthreads();
  if (t == 0) {
    float a = bc2[0];
    for (int j = 0; j < 32; j++) a += zc[j] * Wc2[j];
    out[0] = 1.f / (1.f + expf(-a));
  }
}

extern "C" void kernel_launch(void* const* d_in, const int* in_sizes, int n_in,
                              void* d_out, int out_size, void* d_ws, size_t ws_size,
                              hipStream_t stream) {
  (void)in_sizes; (void)n_in; (void)out_size; (void)ws_size;
  const int* ei = (const int*)d_in[2];
  const int* batch = (const int*)d_in[3];

  char* base = (char*)d_ws;
  size_t off = 0;
  int* deg = (int*)(base + off);          off += ((size_t)NN * 4 + 255) & ~(size_t)255;
  int* cursor = (int*)(base + off);       off += ((size_t)NN * 4 + 255) & ~(size_t)255;
  float* asum = (float*)(base + off);     off += ((size_t)NN * 8 + 255) & ~(size_t)255;
  float* pooled_r = (float*)(base + off); off += ((size_t)16 * GG * 64 * 4 + 255) & ~(size_t)255;
  int* gcnt_r = (int*)(base + off);       off += ((size_t)16 * GG * 4 + 255) & ~(size_t)255;
  size_t zero_words = off / 4;
  int* flag = (int*)(base + off);         off += 256;
  int* offs = (int*)(base + off);         off += ((size_t)(NN + 1) * 4 + 255) & ~(size_t)255;
  float4* recs = (float4*)(base + off);   off += ((size_t)EP * 16 + 255) & ~(size_t)255;
  float* pooled = (float*)(base + off);   off += ((size_t)GG * 64 * 4 + 255) & ~(size_t)255;
  int* gcnt = (int*)(base + off);         off += ((size_t)GG * 4 + 255) & ~(size_t)255;
  float* GI = (float*)(base + off);       off += ((size_t)GG * 192 * 4 + 255) & ~(size_t)255;
  unsigned* xl2p = (unsigned*)(base + off); off += ((size_t)NN * 32 * 4 + 255) & ~(size_t)255;
  float* xr2 = (float*)(base + off);      off += ((size_t)NN * 64 * 4 + 255) & ~(size_t)255;

  const int fidx[24]  = {0,1,4,5,6,7,8,9,10,11,12,13,14,15,16,17,18,19,20,21,22,23,24,25};
  const int fsize[24] = {NN*5, EE*2, 1280,256,1280,256,512,256,256,
                         16384,64,16384,64,128,64,64,
                         12288,12288,192,192,2048,32,32,1};
  float* F[26];
  Cvt24 cd;
  int total = 0;
  for (int i = 0; i < 24; i++) {
    F[fidx[i]] = (float*)(base + off);
    off += ((size_t)fsize[i] * 4 + 255) & ~(size_t)255;
    cd.src[i] = d_in[fidx[i]];
    cd.dst[i] = F[fidx[i]];
    cd.start[i] = total;
    total += fsize[i];
  }
  cd.start[24] = total;

  k_probe_v7<<<1, 64, 0, stream>>>((const unsigned short*)d_in[0], flag);
  k_cvtall_v8<<<(total + 255) / 256, 256, 0, stream>>>(cd, flag, total);
  k_zero_v7<<<(int)((zero_words + 255) / 256), 256, 0, stream>>>((int*)d_ws, (int)zero_words);
  k_count_v7<<<(EE + 255) / 256, 256, 0, stream>>>(ei, F[1], deg, asum);
  k_scan_v7<<<1, 256, 0, stream>>>(deg, offs);
  k_scatter_v12<<<(EP + 255) / 256, 256, 0, stream>>>(ei, F[1], deg, asum, offs, cursor, recs);
  k_gat1_v13<<<(NN + 15) / 16, 256, 0, stream>>>(F[0],
                                                 F[4], F[5], F[6], F[7], F[8], F[9], F[10],
                                                 F[11], F[12], F[13], F[14],
                                                 offs, recs, xl2p, xr2);
  k_gat2_v15<<<(NN + 3) / 4, 256, 0, stream>>>(F[15], F[16], F[17], offs, recs,
                                               (const uint4*)xl2p, xr2, batch,
                                               pooled_r, gcnt_r);
  k_poolsum_v9<<<(GG * 64 + 255) / 256, 256, 0, stream>>>(pooled_r, gcnt_r, pooled, gcnt);
  k_gin_v7<<<(GG * 192 + 255) / 256, 256, 0, stream>>>(pooled, gcnt, F[18], F[20], GI);
  k_gru_v12<<<1, 256, 0, stream>>>(GI, F[19], F[21], F[22], F[23], F[24], F[25],
                                   (float*)d_out);
}

// Round 16
// 693.526 us; speedup vs baseline: 1.2599x; 1.2599x over previous
//
#include <hip/hip_runtime.h>
#include <hip/hip_bf16.h>
#include <hip/hip_fp16.h>

#define NN 50000
#define EE 500000
#define EP 550000
#define GG 64

typedef const __hip_bfloat16* bfp;

__device__ __forceinline__ int clampN(int v) { return (int)(((unsigned)v) % (unsigned)NN); }

// DPP helpers (VALU pipe only, no DS)
#define DPP_ADD(x, ctrl) \
  ((x) + __int_as_float(__builtin_amdgcn_update_dpp(0, __float_as_int(x), ctrl, 0xF, 0xF, true)))

__device__ __forceinline__ float row_red16(float v) {
  v = DPP_ADD(v, 0xB1);    // xor1
  v = DPP_ADD(v, 0x4E);    // xor2
  v = DPP_ADD(v, 0x141);   // row_half_mirror == xor4 once quad-uniform
  v = DPP_ADD(v, 0x140);   // row_mirror == xor8 once 8-uniform
  return v;                // 16-lane-row sum, row-uniform
}

// TRUE xor butterfly across 16-lane slots (valid for per-lane-distinct values):
// ds_swizzle literal xor16 + shfl xor32 (r10/r11-proven).
__device__ __forceinline__ float cross_row(float v) {
  v += __int_as_float(__builtin_amdgcn_ds_swizzle(__float_as_int(v), 0x401F)); // xor16
  v += __shfl_xor(v, 32, 64);                                                  // xor32
  return v;
}

__device__ __forceinline__ float rlane(float v, int l) {
  return __int_as_float(__builtin_amdgcn_readlane(__float_as_int(v), l));
}

// value-op fp16 pack/unpack — NO address-taking (r15's reinterpret_cast of
// &pk.x created allocas -> scratch spill: WRITE_SIZE 101 MB, occupancy 54%).
__device__ __forceinline__ float h2f_lo(unsigned u) {
  return __half2float(__ushort_as_half((unsigned short)(u & 0xFFFFu)));
}
__device__ __forceinline__ float h2f_hi(unsigned u) {
  return __half2float(__ushort_as_half((unsigned short)(u >> 16)));
}
__device__ __forceinline__ unsigned f2h_pack(float a, float b) {
  unsigned lo = (unsigned)__half_as_ushort(__float2half_rn(a));
  unsigned hi = (unsigned)__half_as_ushort(__float2half_rn(b));
  return lo | (hi << 16);
}

__global__ void k_probe_v7(const unsigned short* xraw, int* flag) {
  if (threadIdx.x != 0 || blockIdx.x != 0) return;
  int cnt = 0;
  for (int i = 0; i < 64; i++) {
    unsigned u = ((unsigned)xraw[i]) << 16;
    float v = __uint_as_float(u);
    float a = fabsf(v);
    if (a >= 1e-5f && a <= 100.f) cnt++;
  }
  flag[0] = (cnt >= 56) ? 1 : 0;
}

struct Cvt24 {
  const void* src[24];
  float* dst[24];
  int start[25];
};

__global__ void k_cvtall_v8(Cvt24 d, const int* flag, int total) {
  int idx = blockIdx.x * 256 + threadIdx.x;
  if (idx >= total) return;
  int lo = 0, hi = 24;
  while (hi - lo > 1) {
    int mid = (lo + hi) >> 1;
    if (idx >= d.start[mid]) lo = mid; else hi = mid;
  }
  int i = idx - d.start[lo];
  if (flag[0]) d.dst[lo][i] = __bfloat162float(((bfp)d.src[lo])[i]);
  else         d.dst[lo][i] = ((const float*)d.src[lo])[i];
}

__global__ void k_zero_v7(int* p, int n) {
  int i = blockIdx.x * 256 + threadIdx.x;
  if (i < n) p[i] = 0;
}

__global__ void k_count_v7(const int* ei, const float* ea, int* deg, float* asum) {
  int e = blockIdx.x * 256 + threadIdx.x;
  if (e >= EE) return;
  int dst = clampN(ei[EE + e]);
  atomicAdd(&deg[dst], 1);
  atomicAdd(&asum[2 * dst],     ea[2 * e]);
  atomicAdd(&asum[2 * dst + 1], ea[2 * e + 1]);
}

__global__ void k_scan_v7(const int* deg, int* offs) {
  __shared__ int part[256];
  int t = threadIdx.x;
  int npt = (NN + 255) / 256;
  int lo = t * npt;
  int hi = lo + npt;
  if (hi > NN) hi = NN;
  int sum = 0;
  for (int i = lo; i < hi; i++) sum += deg[i] + 1;
  part[t] = sum;
  __syncthreads();
  for (int o = 1; o < 256; o <<= 1) {
    int add = (t >= o) ? part[t - o] : 0;
    __syncthreads();
    part[t] += add;
    __syncthreads();
  }
  int base = part[t] - sum;
  for (int i = lo; i < hi; i++) {
    offs[i] = base;
    base += deg[i] + 1;
  }
  if (t == 255) offs[NN] = part[255];
}

// self-loop mean folded in
__global__ void k_scatter_v12(const int* ei, const float* ea,
                              const int* deg, const float* asum,
                              const int* offs, int* cursor, float4* recs) {
  int e = blockIdx.x * 256 + threadIdx.x;
  if (e >= EP) return;
  int dst, src;
  float a0, a1;
  if (e < EE) {
    dst = clampN(ei[EE + e]);
    src = clampN(ei[e]);
    a0 = ea[2 * e];
    a1 = ea[2 * e + 1];
  } else {
    dst = e - EE;
    src = dst;
    float d = (float)deg[dst];
    if (d < 1.f) d = 1.f;
    a0 = asum[2 * dst] / d;
    a1 = asum[2 * dst + 1] / d;
  }
  int pos = offs[dst] + atomicAdd(&cursor[dst], 1);
  if (pos >= 0 && pos < EP)
    recs[pos] = make_float4(__int_as_float(src), a0, a1, 0.f);
}

// GAT1: 4 waves x 4 nodes, DPP row-reduce, block-wide lin2 GEMM epilogue;
// xl2 stored FP16-packed (rel err 2^-12, negligible downstream).
__global__ void k_gat1_v16(const float* x,
                           const float* Wl, const float* bl,
                           const float* Wr, const float* br,
                           const float* We, const float* att, const float* bias,
                           const float* Wl2, const float* bl2,
                           const float* Wr2, const float* br2,
                           const int* offs, const float4* recs,
                           unsigned* xl2p, float* xr2) {
  __shared__ float hS[16 * 256];
  int t = threadIdx.x;
  int w = t >> 6;
  int l = t & 63;
  int g = l >> 4;
  int m = l & 15;
  int ibase = blockIdx.x * 16;
  float wl[4][5], wr[4][5], we0v[4], we1v[4], attv[4], blv[4], brv[4], biasv[4];
#pragma unroll
  for (int q = 0; q < 4; q++) {
    int j = g * 64 + m + 16 * q;
#pragma unroll
    for (int k = 0; k < 5; k++) {
      wl[q][k] = Wl[k * 256 + j];
      wr[q][k] = Wr[k * 256 + j];
    }
    we0v[q] = We[j];
    we1v[q] = We[256 + j];
    attv[q] = att[j];
    blv[q] = bl[j];
    brv[q] = br[j];
    biasv[q] = bias[j];
  }
  for (int nn = 0; nn < 4; nn++) {
    int i = ibase + w * 4 + nn;
    if (i >= NN) break;
    float xi[5];
#pragma unroll
    for (int k = 0; k < 5; k++) xi[k] = x[i * 5 + k];
    float xrv[4];
#pragma unroll
    for (int q = 0; q < 4; q++) {
      float a = brv[q];
#pragma unroll
      for (int k = 0; k < 5; k++) a += xi[k] * wr[q][k];
      xrv[q] = a;
    }
    int p0 = offs[i], p1 = offs[i + 1];
    float s = 0.f;
    float acc[4] = {0.f, 0.f, 0.f, 0.f};
    for (int base = p0; base < p1; base += 8) {
      int rem = p1 - base;
      int idx = base + (l & 7);
      if (idx >= p1) idx = p1 - 1;
      float4 rec = recs[idx];
      float xa0 = 0.f, xa1 = 0.f, xa2 = 0.f, xa3 = 0.f, xa4 = 0.f;
      if (l < 8) {
        const float* xp = x + (size_t)__float_as_int(rec.x) * 5;
        xa0 = xp[0]; xa1 = xp[1]; xa2 = xp[2]; xa3 = xp[3]; xa4 = xp[4];
      }
#pragma unroll
      for (int j = 0; j < 8; j++) {
        if (j >= rem) break;
        float xs0 = rlane(xa0, j), xs1 = rlane(xa1, j), xs2 = rlane(xa2, j),
              xs3 = rlane(xa3, j), xs4 = rlane(xa4, j);
        float ea0 = rlane(rec.y, j), ea1 = rlane(rec.z, j);
        float xlv[4];
        float v = 0.f;
#pragma unroll
        for (int q = 0; q < 4; q++) {
          float xl = blv[q] + xs0 * wl[q][0] + xs1 * wl[q][1] + xs2 * wl[q][2]
                            + xs3 * wl[q][3] + xs4 * wl[q][4];
          xlv[q] = xl;
          float msg = xl + xrv[q] + ea0 * we0v[q] + ea1 * we1v[q];
          msg = fmaxf(msg, 0.2f * msg);
          v += msg * attv[q];
        }
        v = row_red16(v);
        float wgt = __expf(v);
        s += wgt;
#pragma unroll
        for (int q = 0; q < 4; q++) acc[q] += wgt * xlv[q];
      }
    }
#pragma unroll
    for (int q = 0; q < 4; q++) {
      float o = acc[q] / s + biasv[q];
      o = (o > 0.f) ? o : (__expf(o) - 1.0f);
      hS[(w * 4 + nn) * 256 + g * 64 + m + 16 * q] = o;
    }
  }
  __syncthreads();
  int c = t & 63;
  int q4 = t >> 6;
  float accl[4] = {0.f, 0.f, 0.f, 0.f};
  float accr[4] = {0.f, 0.f, 0.f, 0.f};
  for (int k = 0; k < 256; k++) {
    float wlv = Wl2[k * 64 + c];
    float wrv = Wr2[k * 64 + c];
#pragma unroll
    for (int n = 0; n < 4; n++) {
      float hv = hS[(q4 * 4 + n) * 256 + k];
      accl[n] += hv * wlv;
      accr[n] += hv * wrv;
    }
  }
  float blc = bl2[c];
  float brc = br2[c];
#pragma unroll
  for (int n = 0; n < 4; n++) {
    int i = ibase + q4 * 4 + n;
    if (i < NN) {
      float vl = accl[n] + blc;
      xr2[(size_t)i * 64 + c] = accr[n] + brc;
      float vo = __int_as_float(__shfl_xor(__float_as_int(vl), 1, 64));
      if ((c & 1) == 0)                      // even lane packs (self, odd-neighbor)
        xl2p[(size_t)i * 32 + (c >> 1)] = f2h_pack(vl, vo);
    }
  }
}

// GAT2 v16: 16-lane slots (r=l>>4: 4 edges in flight), lane owns channels
// 4m..4m+3 via one uint2 (fp16-packed) load. Arrays of 4 -> no spill.
__global__ void k_gat2_v16(const float* We, const float* att, const float* bias,
                           const int* offs, const float4* recs,
                           const uint2* xl2p, const float* xr2, const int* batch,
                           float* pooled_r, int* gcnt_r) {
  int i = blockIdx.x * 4 + (threadIdx.x >> 6);
  if (i >= NN) return;
  int l = threadIdx.x & 63;
  int r = l >> 4;           // edge slot
  int m = l & 15;           // channel group: 4m..4m+3
  int ch0 = m * 4;
  float we0v[4], we1v[4], attv[4], xrcv[4];
#pragma unroll
  for (int cc = 0; cc < 4; cc++) {
    we0v[cc] = We[ch0 + cc];
    we1v[cc] = We[64 + ch0 + cc];
    attv[cc] = att[ch0 + cc];
    xrcv[cc] = xr2[(size_t)i * 64 + ch0 + cc];
  }
  int p0 = offs[i], p1 = offs[i + 1];
  float s = 0.f;
  float acc[4] = {0.f, 0.f, 0.f, 0.f};
  for (int base = p0; base < p1; base += 4) {
    int eidx = base + r;
    bool valid = eidx < p1;
    float4 rec = recs[valid ? eidx : (p1 - 1)];
    uint2 pk = xl2p[(size_t)__float_as_int(rec.x) * 16 + m];
    float xl0 = h2f_lo(pk.x);
    float xl1 = h2f_hi(pk.x);
    float xl2v = h2f_lo(pk.y);
    float xl3 = h2f_hi(pk.y);
    float msg0 = xl0 + xrcv[0] + rec.y * we0v[0] + rec.z * we1v[0];
    float msg1 = xl1 + xrcv[1] + rec.y * we0v[1] + rec.z * we1v[1];
    float msg2 = xl2v + xrcv[2] + rec.y * we0v[2] + rec.z * we1v[2];
    float msg3 = xl3 + xrcv[3] + rec.y * we0v[3] + rec.z * we1v[3];
    msg0 = fmaxf(msg0, 0.2f * msg0);
    msg1 = fmaxf(msg1, 0.2f * msg1);
    msg2 = fmaxf(msg2, 0.2f * msg2);
    msg3 = fmaxf(msg3, 0.2f * msg3);
    float v = msg0 * attv[0] + msg1 * attv[1] + msg2 * attv[2] + msg3 * attv[3];
    v = row_red16(v);                   // this edge's logit (slot-uniform)
    float w = valid ? __expf(v) : 0.f;
    s += w;
    acc[0] += w * xl0;
    acc[1] += w * xl1;
    acc[2] += w * xl2v;
    acc[3] += w * xl3;
  }
  s = cross_row(s);                     // TRUE xor16+xor32 butterfly
#pragma unroll
  for (int cc = 0; cc < 4; cc++) acc[cc] = cross_row(acc[cc]);
  if (r == 0) {                         // lanes m=0..15 cover all 64 channels
    int gsl = (int)(((unsigned)batch[i]) % (unsigned)GG);
    int rep = i & 15;
#pragma unroll
    for (int cc = 0; cc < 4; cc++) {
      float o = acc[cc] / s + bias[ch0 + cc];
      o = (o > 0.f) ? o : (__expf(o) - 1.0f);
      atomicAdd(&pooled_r[rep * (GG * 64) + gsl * 64 + ch0 + cc], o);
    }
    if (m == 0) atomicAdd(&gcnt_r[rep * GG + gsl], 1);
  }
}

__global__ void k_poolsum_v9(const float* pooled_r, const int* gcnt_r,
                             float* pooled, int* gcnt) {
  int i = blockIdx.x * 256 + threadIdx.x;
  if (i < GG * 64) {
    float a = 0.f;
    for (int r = 0; r < 16; r++) a += pooled_r[r * (GG * 64) + i];
    pooled[i] = a;
  }
  if (i < GG) {
    int a = 0;
    for (int r = 0; r < 16; r++) a += gcnt_r[r * GG + i];
    gcnt[i] = a;
  }
}

__global__ void k_gin_v7(const float* pooled, const int* gcnt,
                         const float* Wi, const float* bi, float* GI) {
  int idx = blockIdx.x * 256 + threadIdx.x;
  if (idx >= GG * 192) return;
  int ts = idx / 192;
  int j = idx % 192;
  float a = 0.f;
  for (int k = 0; k < 64; k++) a += pooled[ts * 64 + k] * Wi[k * 192 + j];
  float cnt = (float)gcnt[ts];
  if (cnt < 1.f) cnt = 1.f;
  GI[idx] = a / cnt + bi[j];
}

// GRU + classifier; f32 output.
__global__ void k_gru_v12(const float* GI, const float* Wh, const float* bh,
                          const float* Wc1, const float* bc1,
                          const float* Wc2, const float* bc2, float* out) {
  __shared__ float WhS[64 * 192];
  __shared__ float hS[64];
  __shared__ float ghS[192];
  __shared__ float zc[32];
  int t = threadIdx.x;
  for (int idx = t; idx < 64 * 192; idx += 256) WhS[idx] = Wh[idx];
  if (t < 64) hS[t] = 0.f;
  __syncthreads();
  for (int ts = 0; ts < GG; ++ts) {
    if (t < 192) {
      float a = bh[t];
#pragma unroll 8
      for (int k = 0; k < 64; k++) a += hS[k] * WhS[k * 192 + t];
      ghS[t] = a;
    }
    __syncthreads();
    if (t < 64) {
      float r = 1.f / (1.f + expf(-(GI[ts * 192 + t] + ghS[t])));
      float z = 1.f / (1.f + expf(-(GI[ts * 192 + 64 + t] + ghS[64 + t])));
      float n = tanhf(GI[ts * 192 + 128 + t] + r * ghS[128 + t]);
      hS[t] = (1.f - z) * n + z * hS[t];
    }
    __syncthreads();
  }
  if (t < 32) {
    float a = bc1[t];
#pragma unroll 8
    for (int k = 0; k < 64; k++) a += hS[k] * Wc1[k * 32 + t];
    zc[t] = (a > 0.f) ? a : 0.f;
  }
  __syncthreads();
  if (t == 0) {
    float a = bc2[0];
    for (int j = 0; j < 32; j++) a += zc[j] * Wc2[j];
    out[0] = 1.f / (1.f + expf(-a));
  }
}

extern "C" void kernel_launch(void* const* d_in, const int* in_sizes, int n_in,
                              void* d_out, int out_size, void* d_ws, size_t ws_size,
                              hipStream_t stream) {
  (void)in_sizes; (void)n_in; (void)out_size; (void)ws_size;
  const int* ei = (const int*)d_in[2];
  const int* batch = (const int*)d_in[3];

  char* base = (char*)d_ws;
  size_t off = 0;
  int* deg = (int*)(base + off);          off += ((size_t)NN * 4 + 255) & ~(size_t)255;
  int* cursor = (int*)(base + off);       off += ((size_t)NN * 4 + 255) & ~(size_t)255;
  float* asum = (float*)(base + off);     off += ((size_t)NN * 8 + 255) & ~(size_t)255;
  float* pooled_r = (float*)(base + off); off += ((size_t)16 * GG * 64 * 4 + 255) & ~(size_t)255;
  int* gcnt_r = (int*)(base + off);       off += ((size_t)16 * GG * 4 + 255) & ~(size_t)255;
  size_t zero_words = off / 4;
  int* flag = (int*)(base + off);         off += 256;
  int* offs = (int*)(base + off);         off += ((size_t)(NN + 1) * 4 + 255) & ~(size_t)255;
  float4* recs = (float4*)(base + off);   off += ((size_t)EP * 16 + 255) & ~(size_t)255;
  float* pooled = (float*)(base + off);   off += ((size_t)GG * 64 * 4 + 255) & ~(size_t)255;
  int* gcnt = (int*)(base + off);         off += ((size_t)GG * 4 + 255) & ~(size_t)255;
  float* GI = (float*)(base + off);       off += ((size_t)GG * 192 * 4 + 255) & ~(size_t)255;
  unsigned* xl2p = (unsigned*)(base + off); off += ((size_t)NN * 32 * 4 + 255) & ~(size_t)255;
  float* xr2 = (float*)(base + off);      off += ((size_t)NN * 64 * 4 + 255) & ~(size_t)255;

  const int fidx[24]  = {0,1,4,5,6,7,8,9,10,11,12,13,14,15,16,17,18,19,20,21,22,23,24,25};
  const int fsize[24] = {NN*5, EE*2, 1280,256,1280,256,512,256,256,
                         16384,64,16384,64,128,64,64,
                         12288,12288,192,192,2048,32,32,1};
  float* F[26];
  Cvt24 cd;
  int total = 0;
  for (int i = 0; i < 24; i++) {
    F[fidx[i]] = (float*)(base + off);
    off += ((size_t)fsize[i] * 4 + 255) & ~(size_t)255;
    cd.src[i] = d_in[fidx[i]];
    cd.dst[i] = F[fidx[i]];
    cd.start[i] = total;
    total += fsize[i];
  }
  cd.start[24] = total;

  k_probe_v7<<<1, 64, 0, stream>>>((const unsigned short*)d_in[0], flag);
  k_cvtall_v8<<<(total + 255) / 256, 256, 0, stream>>>(cd, flag, total);
  k_zero_v7<<<(int)((zero_words + 255) / 256), 256, 0, stream>>>((int*)d_ws, (int)zero_words);
  k_count_v7<<<(EE + 255) / 256, 256, 0, stream>>>(ei, F[1], deg, asum);
  k_scan_v7<<<1, 256, 0, stream>>>(deg, offs);
  k_scatter_v12<<<(EP + 255) / 256, 256, 0, stream>>>(ei, F[1], deg, asum, offs, cursor, recs);
  k_gat1_v16<<<(NN + 15) / 16, 256, 0, stream>>>(F[0],
                                                 F[4], F[5], F[6], F[7], F[8], F[9], F[10],
                                                 F[11], F[12], F[13], F[14],
                                                 offs, recs, xl2p, xr2);
  k_gat2_v16<<<(NN + 3) / 4, 256, 0, stream>>>(F[15], F[16], F[17], offs, recs,
                                               (const uint2*)xl2p, xr2, batch,
                                               pooled_r, gcnt_r);
  k_poolsum_v9<<<(GG * 64 + 255) / 256, 256, 0, stream>>>(pooled_r, gcnt_r, pooled, gcnt);
  k_gin_v7<<<(GG * 192 + 255) / 256, 256, 0, stream>>>(pooled, gcnt, F[18], F[20], GI);
  k_gru_v12<<<1, 256, 0, stream>>>(GI, F[19], F[21], F[22], F[23], F[24], F[25],
                                   (float*)d_out);
}